// Round 6
// baseline (289.117 us; speedup 1.0000x reference)
//
#include <hip/hip_runtime.h>

#define LSEQ 96
#define DM 256
#define NH 8
#define DH 32
#define WIN 16

typedef unsigned short u16;
typedef unsigned int u32;
typedef _Float16 f16;
typedef __attribute__((ext_vector_type(2))) __fp16 fp16x2_raw;
typedef __attribute__((ext_vector_type(4))) _Float16 f16x4;
typedef __attribute__((ext_vector_type(8))) _Float16 f16x8;
typedef __attribute__((ext_vector_type(4))) float f32x4;
typedef __attribute__((ext_vector_type(4))) u32 u32x4;

#define MFMA(a, b, c) __builtin_amdgcn_mfma_f32_16x16x32_f16((a), (b), (c), 0, 0, 0)

static __device__ __forceinline__ u32 pkrtz(float a, float b) {
    fp16x2_raw t = __builtin_amdgcn_cvt_pkrtz(a, b);
    return __builtin_bit_cast(u32, t);
}
static __device__ __forceinline__ f16x8 mk8(u32 w0, u32 w1, u32 w2, u32 w3) {
    u32x4 t = {w0, w1, w2, w3};
    return __builtin_bit_cast(f16x8, t);
}

// Gather one MFMA B-fragment (16x16x32 f16) of W directly from the fp32
// row-major [256][256] matrix:
//   lane j-th element = W[k][col], k = ks*32 + (lane>>4)*8 + j,
//   col = nt*16 + (lane&15).
// 8 stride-1KB dword loads per lane; weights are 1MB total -> L2-resident
// across all 1024 blocks. RNE converts. Read as an A-frag the same bytes
// are W^T (used for the Q-on-the-fly trick).
static __device__ __forceinline__ f16x8 gfrag(const float* __restrict__ W,
                                              int nt, int ks, int lane) {
    const float* p = W + (size_t)((ks << 5) + ((lane >> 4) << 3)) * 256
                       + (nt << 4) + (lane & 15);
    f16x8 r;
#pragma unroll
    for (int j = 0; j < 8; ++j) r[j] = (f16)p[(size_t)j * 256];
    return r;
}

// ---------------------------------------------------------------------------
// fused_attn: ONE kernel, one block per sequence, 512 threads = 8 waves =
// 8 heads. No d_ws, no prep kernel (round-5 counters showed a constant
// ~115-120us bench-vs-rocprof gap that tracks the prep/d_ws path, not the
// fused kernel).
// Structure (2 barriers):
//   stage X -> b1 -> [phase1: K,V all heads (self cols)] ->
//   [phase2 barrier-free: per-wave head: Q-on-the-fly, S^T, in-reg softmax,
//    PV] -> [Wo frag gather (hoisted)] -> O-dump into own K cols -> b2 ->
//   [phase3: Wo] -> store.
// LDS (151552 B -> 1 block/CU):
//   Xs [96][256] f16, 16B-granule XOR swizzle (^ row&7)   49152 B
//   KO [96][256] f16, same swizzle; K then O (same map)   49152 B
//   VT [256][104] f16 (V^T: row = d-global, col = seq j)  53248 B
// waves_per_eu(2,2): full 256-reg unified budget, no spill (r5-verified).
// ---------------------------------------------------------------------------
__global__ __attribute__((amdgpu_flat_work_group_size(512, 512),
                          amdgpu_waves_per_eu(2, 2)))
void fused_attn(const float* __restrict__ Z,  const float* __restrict__ Wq,
                const float* __restrict__ Wk, const float* __restrict__ Wv,
                const float* __restrict__ Wo, const float* __restrict__ rb,
                float* __restrict__ out)
{
    __shared__ f16 Xs[96 * 256];
    __shared__ f16 KO[96 * 256];
    __shared__ f16 VT[256 * 104];

    const int tid  = threadIdx.x;
    const int n    = blockIdx.x;
    const int w    = tid >> 6;        // wave = head
    const int lane = tid & 63;
    const int g    = lane >> 4;       // 16-lane group 0..3
    const int qr   = lane & 15;

    const f32x4 zf4 = {0.f, 0.f, 0.f, 0.f};

    // ---- stage X as fp16, XOR-swizzled 16B granules ----
    const float4* Zv = (const float4*)(Z + (size_t)n * (LSEQ * DM));
#pragma unroll
    for (int r2 = 0; r2 < 12; ++r2) {
        int e = tid + (r2 << 9);
        float4 x = Zv[e];
        int row = e >> 6, c4 = e & 63;
        int gr = c4 >> 1, hf = c4 & 1;
        f16x4 hv = {(f16)x.x, (f16)x.y, (f16)x.z, (f16)x.w};
        *(f16x4*)&Xs[row * 256 + (((gr ^ (row & 7)) << 3) + hf * 4)] = hv;
    }
    __syncthreads();   // b1: Xs visible

    // ===== phase 1: K, V; wave w -> col-tiles nt = 2w, 2w+1 ====
#pragma unroll
    for (int mi = 0; mi < 2; ++mi) {
        const float* W = (mi == 0) ? Wk : Wv;
#pragma unroll
        for (int ntl = 0; ntl < 2; ++ntl) {
            int nt = 2 * w + ntl;
            f16x8 B[8];
#pragma unroll
            for (int ks = 0; ks < 8; ++ks) B[ks] = gfrag(W, nt, ks, lane);
#pragma unroll
            for (int m = 0; m < 6; ++m) {
                int arow = m * 16 + qr, ra = arow & 7;
                const f16* xb = &Xs[arow * 256];
                f32x4 a0 = zf4, a1 = zf4;
#pragma unroll
                for (int ks = 0; ks < 8; ks += 2) {
                    a0 = MFMA(*(const f16x8*)&xb[((4*ks + g) ^ ra) << 3],     B[ks],   a0);
                    a1 = MFMA(*(const f16x8*)&xb[((4*(ks+1) + g) ^ ra) << 3], B[ks+1], a1);
                }
                f32x4 acc = a0 + a1;
                if (mi == 0) {         // K -> KO, row-major swizzled, self cols
                    int col = nt * 16 + qr, gc = col >> 3, cl = col & 7;
#pragma unroll
                    for (int r = 0; r < 4; ++r) {
                        int i = m * 16 + 4 * g + r;
                        KO[i * 256 + ((gc ^ (i & 7)) << 3) + cl] = (f16)acc[r];
                    }
                } else {               // V -> VT[d][j], 4 consecutive j
                    int vrow = nt * 16 + qr;
                    f16x4 vv = {(f16)acc[0], (f16)acc[1], (f16)acc[2], (f16)acc[3]};
                    *(f16x4*)&VT[vrow * 104 + m * 16 + 4 * g] = vv;
                }
            }
        }
    }
    // no barrier: phase 2 reads only this wave's own K/V cols + Xs (b1)

    // ===== phase 2: wave w == head w, barrier-free =====
    f16x8 wq0[8], wq1[8];
#pragma unroll
    for (int ks = 0; ks < 8; ++ks) {
        wq0[ks] = gfrag(Wq, 2 * w,     ks, lane);
        wq1[ks] = gfrag(Wq, 2 * w + 1, ks, lane);
    }

    // bias table: 24 per-lane values, one per (tile-distance ds, r)
    const float L2E = 1.4426950408889634f;
    const float SC2 = 0.17677669529663687f * L2E;   // (1/sqrt(32))*log2(e)
    float bval[6][4];
#pragma unroll
    for (int ds = 0; ds < 6; ++ds)
#pragma unroll
        for (int r = 0; r < 4; ++r) {
            int diff = 16 * ds + (qr - 4 * g - r);   // (i-j) mod 96, via ds
            if (diff < 0) diff += 96;
            int dc = diff < 96 - diff ? diff : 96 - diff;
            bval[ds][r] = (dc <= WIN) ? rb[w * 96 + diff] * L2E : -1.0e30f;
        }

    const int  sl0 = ((g & 1) << 5) | qr;   // gather source lane (low half)
    const bool ghi = (g >= 2);

    f32x4 osv0[6], osv1[6];

#pragma unroll
    for (int s = 0; s < 6; ++s) {
        // ---- Q^T on the fly: C[d][i] = mfma(A=Wq^T (gathered), B=X rows) ----
        int xrow = s * 16 + qr, rx = xrow & 7;
        const f16* xb = &Xs[xrow * 256];
        f32x4 qc0 = zf4, qc1 = zf4;
#pragma unroll
        for (int ks = 0; ks < 8; ++ks) {
            f16x8 xf = *(const f16x8*)&xb[((4 * ks + g) ^ rx) << 3];
            qc0 = MFMA(wq0[ks], xf, qc0);
            qc1 = MFMA(wq1[ks], xf, qc1);
        }
        // lane holds Q[i=16s+qr][d = nc*16 + 4g + r] -> shuffle to B-frag
        u32 q00 = pkrtz(qc0[0], qc0[1]), q01 = pkrtz(qc0[2], qc0[3]);
        u32 q10 = pkrtz(qc1[0], qc1[1]), q11 = pkrtz(qc1[2], qc1[3]);
        u32 a0 = __shfl((int)q00, sl0),      a1 = __shfl((int)q01, sl0);
        u32 a2 = __shfl((int)q00, sl0 + 16), a3 = __shfl((int)q01, sl0 + 16);
        u32 b0 = __shfl((int)q10, sl0),      b1 = __shfl((int)q11, sl0);
        u32 b2 = __shfl((int)q10, sl0 + 16), b3 = __shfl((int)q11, sl0 + 16);
        f16x8 qf = mk8(ghi ? b0 : a0, ghi ? b1 : a1, ghi ? b2 : a2, ghi ? b3 : a3);

        // ---- S^T = mfma(A=K rows, B=Q): lane gets row i=16s+qr, 24 cols ----
        f32x4 st[6];
#pragma unroll
        for (int tt = 0; tt < 6; ++tt) {
            int krow = tt * 16 + qr;
            f16x8 kf = *(const f16x8*)&KO[krow * 256 + (((4 * w + g) ^ (krow & 7)) << 3)];
            st[tt] = MFMA(kf, qf, zf4);
        }

        // ---- masked softmax, in-register (partners: lane^16, lane^32) ----
        float vv[6][4];
        float mx = -3.0e38f;
#pragma unroll
        for (int tt = 0; tt < 6; ++tt) {
#pragma unroll
            for (int r = 0; r < 4; ++r) {
                float vx = st[tt][r] * SC2 + bval[(s - tt + 6) % 6][r];
                vv[tt][r] = vx;
                mx = fmaxf(mx, vx);
            }
        }
        mx = fmaxf(mx, __shfl_xor(mx, 16));
        mx = fmaxf(mx, __shfl_xor(mx, 32));
        float sum = 0.f;
#pragma unroll
        for (int tt = 0; tt < 6; ++tt)
#pragma unroll
            for (int r = 0; r < 4; ++r) {
                float e = __builtin_amdgcn_exp2f(vv[tt][r] - mx);
                vv[tt][r] = e;
                sum += e;
            }
        sum += __shfl_xor(sum, 16);
        sum += __shfl_xor(sum, 32);
        float inv = __builtin_amdgcn_rcpf(sum);
        u32 pk[6][2];
#pragma unroll
        for (int tt = 0; tt < 6; ++tt) {
            pk[tt][0] = pkrtz(vv[tt][0] * inv, vv[tt][1] * inv);
            pk[tt][1] = pkrtz(vv[tt][2] * inv, vv[tt][3] * inv);
        }

        // ---- PV: A = P (shuffled to A-frag), B = V^T rows ----
        f32x4 o0 = zf4, o1 = zf4;
#pragma unroll
        for (int ks = 0; ks < 3; ++ks) {
            u32 c0 = __shfl((int)pk[2*ks][0], sl0),      c1 = __shfl((int)pk[2*ks][1], sl0);
            u32 c2 = __shfl((int)pk[2*ks][0], sl0 + 16), c3 = __shfl((int)pk[2*ks][1], sl0 + 16);
            u32 d0 = __shfl((int)pk[2*ks+1][0], sl0),      d1 = __shfl((int)pk[2*ks+1][1], sl0);
            u32 d2 = __shfl((int)pk[2*ks+1][0], sl0 + 16), d3 = __shfl((int)pk[2*ks+1][1], sl0 + 16);
            f16x8 pf = mk8(ghi ? d0 : c0, ghi ? d1 : c1, ghi ? d2 : c2, ghi ? d3 : c3);
            const f16* vp = &VT[(32 * w + qr) * 104 + 32 * ks + 8 * g];
            o0 = MFMA(pf, *(const f16x8*)vp, o0);
            o1 = MFMA(pf, *(const f16x8*)(vp + 16 * 104), o1);
        }
        osv0[s] = o0;
        osv1[s] = o1;
    }

    // ---- Wo fragment gather, hoisted: L2 latency hides under O-dump + b2 ----
    f16x8 wo0[8], wo1[8];
#pragma unroll
    for (int ks = 0; ks < 8; ++ks) {
        wo0[ks] = gfrag(Wo, 2 * w,     ks, lane);
        wo1[ks] = gfrag(Wo, 2 * w + 1, ks, lane);
    }

    // ---- O dump into KO cols [32w, 32w+32) (self region; in-wave ordered) --
#pragma unroll
    for (int s = 0; s < 6; ++s) {
        int col0 = 32 * w + qr, gc0 = col0 >> 3, cl = col0 & 7;
        int gc1 = (col0 + 16) >> 3;
#pragma unroll
        for (int r = 0; r < 4; ++r) {
            int i = 16 * s + 4 * g + r;
            KO[i * 256 + ((gc0 ^ (i & 7)) << 3) + cl] = (f16)osv0[s][r];
            KO[i * 256 + ((gc1 ^ (i & 7)) << 3) + cl] = (f16)osv1[s][r];
        }
    }
    __syncthreads();   // b2: full O visible

    // ===== phase 3: out = O @ Wo, wave w -> out cols [32w, 32w+32) =====
    f32x4 oacc0[6], oacc1[6];
#pragma unroll
    for (int m = 0; m < 6; ++m) {
        oacc0[m] = zf4;
        oacc1[m] = zf4;
    }
#pragma unroll
    for (int m = 0; m < 6; ++m) {
        int arow = 16 * m + qr, ra = arow & 7;
        const f16* ab = &KO[arow * 256];
#pragma unroll
        for (int ks = 0; ks < 8; ++ks) {
            f16x8 af = *(const f16x8*)&ab[((4 * ks + g) ^ ra) << 3];
            oacc0[m] = MFMA(af, wo0[ks], oacc0[m]);
            oacc1[m] = MFMA(af, wo1[ks], oacc1[m]);
        }
    }

    // ---- store ----
    float* on = out + (size_t)n * (LSEQ * DM);
    int d0 = 32 * w + qr, d1 = d0 + 16;
#pragma unroll
    for (int m = 0; m < 6; ++m) {
#pragma unroll
        for (int r = 0; r < 4; ++r) {
            int i = 16 * m + 4 * g + r;
            on[i * 256 + d0] = oacc0[m][r];
            on[i * 256 + d1] = oacc1[m][r];
        }
    }
}

extern "C" void kernel_launch(void* const* d_in, const int* in_sizes, int n_in,
                              void* d_out, int out_size, void* d_ws, size_t ws_size,
                              hipStream_t stream) {
    const float* Z  = (const float*)d_in[0];
    const float* Wq = (const float*)d_in[1];
    const float* Wk = (const float*)d_in[2];
    const float* Wv = (const float*)d_in[3];
    const float* Wo = (const float*)d_in[4];
    const float* rbp = (const float*)d_in[5];
    float* out = (float*)d_out;
    (void)d_ws; (void)ws_size;   // deliberately unused (round-6 theory)

    fused_attn<<<1024, 512, 0, stream>>>(Z, Wq, Wk, Wv, Wo, rbp, out);
}